// Round 13
// baseline (1929.519 us; speedup 1.0000x reference)
//
#include <hip/hip_runtime.h>

#define DIM 128
#define NCLS 10

// ---------------- CSR build ----------------
__global__ void k_hist(const int* __restrict__ ei, int E, int* __restrict__ deg) {
    int e = blockIdx.x * 256 + threadIdx.x;
    if (e < E) atomicAdd(&deg[ei[E + e]], 1);   // v = ei[1][e]
}

__global__ void k_scan1(const int* __restrict__ deg, int* __restrict__ row_start,
                        int* __restrict__ bsum, int n) {
    int tid = threadIdx.x;
    int base = blockIdx.x * 1024 + tid * 4;
    int v0 = 0, v1 = 0, v2 = 0, v3 = 0;
    if (base + 3 < n) {
        int4 t = *(const int4*)(deg + base);
        v0 = t.x; v1 = t.y; v2 = t.z; v3 = t.w;
    } else {
        if (base + 0 < n) v0 = deg[base + 0];
        if (base + 1 < n) v1 = deg[base + 1];
        if (base + 2 < n) v2 = deg[base + 2];
        if (base + 3 < n) v3 = deg[base + 3];
    }
    int s = v0 + v1 + v2 + v3;
    int lane = tid & 63, w = tid >> 6;
    int inc = s;
#pragma unroll
    for (int o = 1; o < 64; o <<= 1) {
        int t = __shfl_up(inc, o);
        if (lane >= o) inc += t;
    }
    __shared__ int wsum[4];
    if (lane == 63) wsum[w] = inc;
    __syncthreads();
    int woff = 0;
    for (int i = 0; i < w; i++) woff += wsum[i];
    int run = woff + inc - s;
    if (base + 0 < n) row_start[base + 0] = run; run += v0;
    if (base + 1 < n) row_start[base + 1] = run; run += v1;
    if (base + 2 < n) row_start[base + 2] = run; run += v2;
    if (base + 3 < n) row_start[base + 3] = run;
    if (tid == 0) bsum[blockIdx.x] = wsum[0] + wsum[1] + wsum[2] + wsum[3];
}

__global__ void k_scan2(int* __restrict__ bsum, int nb) {
    int tid = threadIdx.x;
    if (nb <= 64) {
        int v = (tid < nb) ? bsum[tid] : 0;
        int inc = v;
#pragma unroll
        for (int o = 1; o < 64; o <<= 1) {
            int t = __shfl_up(inc, o);
            if (tid >= o) inc += t;
        }
        if (tid < nb) bsum[tid] = inc - v;
    } else if (tid == 0) {
        int acc = 0;
        for (int i = 0; i < nb; i++) { int t = bsum[i]; bsum[i] = acc; acc += t; }
    }
}

__global__ void k_scan3(int* __restrict__ row_start, int* __restrict__ cursor,
                        const int* __restrict__ bsum, int n, int E) {
    int i = blockIdx.x * 256 + threadIdx.x;
    if (i < n) {
        int r = row_start[i] + bsum[i >> 10];
        row_start[i] = r;
        cursor[i] = r;
    }
    if (i == n) row_start[n] = E;
}

__global__ void k_fill(const int* __restrict__ ei, int E, int* __restrict__ cursor,
                       int* __restrict__ csr) {
    int e = blockIdx.x * 256 + threadIdx.x;
    if (e < E) {
        int u = ei[e], v = ei[E + e];
        int pos = atomicAdd(&cursor[v], 1);
        csr[pos] = u;
    }
}

// ---------------- action gates: thread per node, 16B/neighbor gather ----------------
// Also zeroes is_b (set by k_aggw which runs next on the stream).
__global__ void k_action(const float* __restrict__ proj, const int* __restrict__ row_start,
                         const int* __restrict__ csr,
                         const float* __restrict__ bain, const float* __restrict__ baon,
                         const float* __restrict__ gin_l, const float* __restrict__ gout_l,
                         int* __restrict__ in_bit, int* __restrict__ out_bit,
                         int* __restrict__ is_b, int n) {
    int v = blockIdx.x * 256 + threadIdx.x;
    if (v >= n) return;
    is_b[v] = 0;
    int b0 = row_start[v], b1 = row_start[v + 1];
    double a0 = 0.0, a1 = 0.0, a2 = 0.0, a3 = 0.0;
    for (int e = b0; e < b1; e++) {
        int u = csr[e];
        float4 p = *(const float4*)(proj + (size_t)u * 8);
        a0 += p.x; a1 += p.y; a2 += p.z; a3 += p.w;
    }
    float4 r = *(const float4*)(proj + (size_t)v * 8 + 4);
    float2 gi = *(const float2*)(gin_l + (size_t)v * 2);
    float2 go = *(const float2*)(gout_l + (size_t)v * 2);
    float li0 = (float)a0 + r.x + bain[0] + gi.x;
    float li1 = (float)a1 + r.y + bain[1] + gi.y;
    float lo0 = (float)a2 + r.z + baon[0] + go.x;
    float lo1 = (float)a3 + r.w + baon[1] + go.y;
    in_bit[v]  = (li0 >= li1) ? 1 : 0;   // argmax==0 on tie
    out_bit[v] = (lo0 >= lo1) ? 1 : 0;
}

// ---------------- gated aggregation + is_b/is_l bookkeeping ----------------
// f64 accumulate: CSR fill order is atomic-nondeterministic; f64 makes the
// rounded f32 sums replay-stable (gate margins can be ~1e-5).
__global__ void k_aggw(const float* __restrict__ hn, const int* __restrict__ row_start,
                       const int* __restrict__ csr, const int* __restrict__ in_bit,
                       const int* __restrict__ out_bit,
                       int* __restrict__ is_b, int* __restrict__ is_l,
                       float* __restrict__ aggw, int n) {
    int wid = (blockIdx.x * 256 + threadIdx.x) >> 6;
    int lane = threadIdx.x & 63;
    if (wid >= n) return;
    int d0 = lane * 2;
    double ax = 0.0, ay = 0.0;
    int anyg = 0;
    if (in_bit[wid]) {
        int base = row_start[wid], end = row_start[wid + 1];
        for (int off = base; off < end; off += 64) {
            int m = min(64, end - off);
            int myu = 0, myb = 0;
            if (lane < m) { myu = csr[off + lane]; myb = out_bit[myu]; }
            unsigned long long mask = __ballot(myb != 0);
            anyg |= (mask != 0ull);
            while (mask) {
                int i = __ffsll((unsigned long long)mask) - 1;
                mask &= mask - 1;
                int u = __shfl(myu, i);
                if (lane == 0) is_b[u] = 1;   // benign race: same value
                float2 t = *(const float2*)(hn + (size_t)u * DIM + d0);
                ax += t.x; ay += t.y;
            }
        }
    }
    if (lane == 0) is_l[wid] = anyg;
    ((float2*)(aggw + (size_t)wid * DIM))[lane] = make_float2((float)ax, (float)ay);
}

// ---------------- GEMM: 64x128 tile, 256 threads, TM=4 x TN=8, LDS dbuf --------------
// out = [LN]( [A +] relu(A@W1 [+ B@W2] + bias) )
// Shape (r4-r12 conclusion): TM=4@256thr is the only shape whose grid (782)
// fills the machine at n=50000; TM=8 variants are grid-starved (r7/r12).
// r8 = this shape single-buffered: 85us with ~38us staging/barrier exposure.
// This round: classic LDS double-buffer -- ONE barrier per chunk, prefetch of
// chunk t+1 issued before computing chunk t (global latency hides under 1024
// FMAs), regs->LDS commit after compute. This is r3's structure; r3 spilled
// because it ran at the compiler's default 64-reg squeeze. waves_per_eu(2,4)
// gives a 256-reg budget; live ~95 (32 acc + 24 prefetch + 16 A + 8 W + addr).
// LDS 2x25.2KB=50.4KB -> 3 blocks/CU == what the 782-block grid supplies anyway.
// Row r's 128 cols live in the 16 lanes sharing ty -> shfl_xor(1,2,4,8) row
// reduce (LN, PROJ, DEC). In-place safe (out==A): block only touches own rows.
template <int HAS_B, int SKIP, int DO_LN, int DO_PROJ, int DO_STATES, int DO_DEC, int WRITE_H>
__launch_bounds__(256)
__attribute__((amdgpu_waves_per_eu(2, 4)))
__global__ void k_gemm(const float* __restrict__ A, const float* __restrict__ W1,
                       const float* __restrict__ B, const float* __restrict__ W2,
                       const float* __restrict__ bias,
                       const float* __restrict__ ln_g, const float* __restrict__ ln_b,
                       const float* __restrict__ Wain, const float* __restrict__ Waon,
                       const float* __restrict__ Wair, const float* __restrict__ Waor,
                       const int* __restrict__ is_b, const int* __restrict__ is_l,
                       const float* __restrict__ Wdec, const float* __restrict__ bdec,
                       float* __restrict__ out, float* __restrict__ proj,
                       float* __restrict__ states_l, float* __restrict__ dec_out, int n) {
    __shared__ float sW[2][32][128];
    __shared__ float sA[2][64][36];
    int tid = threadIdx.x;
    int rowBase = blockIdx.x * 64;
    int ty = tid >> 4, tx = tid & 15;
    int c0 = tx * 4, c1 = 64 + tx * 4;
    const int T = 4 * (1 + HAS_B);
    int lr = tid >> 3, lc4 = (tid & 7) * 4;   // A staging: rows lr, lr+32

    float acc[4][8];
#pragma unroll
    for (int i = 0; i < 4; i++)
#pragma unroll
        for (int j = 0; j < 8; j++) acc[i][j] = 0.f;

    float4 wpre[4], apre0, apre1;
    auto prefetch = [&](int t) {
        const float* Ap = (HAS_B && t >= 4) ? B : A;
        const float* Wp = (HAS_B && t >= 4) ? W2 : W1;
        int kc = (t & 3) * 32;
        const float4* src = (const float4*)(Wp + kc * DIM);
#pragma unroll
        for (int i = 0; i < 4; i++) wpre[i] = src[tid + i * 256];
        apre0 = (rowBase + lr < n)
            ? *(const float4*)(Ap + (size_t)(rowBase + lr) * DIM + kc + lc4)
            : make_float4(0.f, 0.f, 0.f, 0.f);
        apre1 = (rowBase + lr + 32 < n)
            ? *(const float4*)(Ap + (size_t)(rowBase + lr + 32) * DIM + kc + lc4)
            : make_float4(0.f, 0.f, 0.f, 0.f);
    };
    auto commit = [&](int b) {
        float4* dst = (float4*)(&sW[b][0][0]);
#pragma unroll
        for (int i = 0; i < 4; i++) dst[tid + i * 256] = wpre[i];
        *(float4*)&sA[b][lr][lc4] = apre0;
        *(float4*)&sA[b][lr + 32][lc4] = apre1;
    };

    prefetch(0);
    commit(0);
    __syncthreads();
    for (int t = 0; t < T; t++) {
        int b = t & 1;
        if (t + 1 < T) prefetch(t + 1);   // in flight during compute below
#pragma unroll
        for (int kk = 0; kk < 32; kk += 4) {
            float4 a[4];
#pragma unroll
            for (int i = 0; i < 4; i++) a[i] = *(const float4*)&sA[b][i * 16 + ty][kk];
#pragma unroll
            for (int q = 0; q < 4; q++) {
                float4 w0 = *(const float4*)&sW[b][kk + q][c0];
                float4 w1 = *(const float4*)&sW[b][kk + q][c1];
#pragma unroll
                for (int i = 0; i < 4; i++) {
                    float av = (&a[i].x)[q];
                    acc[i][0] += av * w0.x;
                    acc[i][1] += av * w0.y;
                    acc[i][2] += av * w0.z;
                    acc[i][3] += av * w0.w;
                    acc[i][4] += av * w1.x;
                    acc[i][5] += av * w1.y;
                    acc[i][6] += av * w1.z;
                    acc[i][7] += av * w1.w;
                }
            }
        }
        if (t + 1 < T) commit(b ^ 1);     // waits vmcnt; other buffer, no race
        __syncthreads();                  // one barrier per chunk
    }

    // ---- decoder weight staging (reuses sW space; main loop done with it) ----
    float* sWd = (float*)&sW[0][0][0];   // [NCLS][DIM] transposed
    if (DO_DEC) {
        for (int i = tid; i < NCLS * DIM; i += 256) {
            int d = i / NCLS, c = i % NCLS;
            sWd[c * DIM + d] = Wdec[i];
        }
        __syncthreads();
    }

    float4 bias0 = *(const float4*)&bias[c0];
    float4 bias1 = *(const float4*)&bias[c1];
    float bv[8] = {bias0.x, bias0.y, bias0.z, bias0.w, bias1.x, bias1.y, bias1.z, bias1.w};
    float gv[8], bbv[8];
    if (DO_LN) {
        float4 g0 = *(const float4*)&ln_g[c0];
        float4 g1 = *(const float4*)&ln_g[c1];
        float4 lb0 = *(const float4*)&ln_b[c0];
        float4 lb1 = *(const float4*)&ln_b[c1];
        gv[0]=g0.x; gv[1]=g0.y; gv[2]=g0.z; gv[3]=g0.w; gv[4]=g1.x; gv[5]=g1.y; gv[6]=g1.z; gv[7]=g1.w;
        bbv[0]=lb0.x; bbv[1]=lb0.y; bbv[2]=lb0.z; bbv[3]=lb0.w; bbv[4]=lb1.x; bbv[5]=lb1.y; bbv[6]=lb1.z; bbv[7]=lb1.w;
    }

#pragma unroll
    for (int i = 0; i < 4; i++) {
        int r = rowBase + i * 16 + ty;
        if (r >= n) continue;   // uniform across the 16 lanes sharing ty
        float v[8];
        if (SKIP) {
            float4 s0 = *(const float4*)(A + (size_t)r * DIM + c0);
            float4 s1 = *(const float4*)(A + (size_t)r * DIM + c1);
            float sv[8] = {s0.x, s0.y, s0.z, s0.w, s1.x, s1.y, s1.z, s1.w};
#pragma unroll
            for (int j = 0; j < 8; j++) v[j] = fmaxf(acc[i][j] + bv[j], 0.f) + sv[j];
        } else {
#pragma unroll
            for (int j = 0; j < 8; j++) v[j] = fmaxf(acc[i][j] + bv[j], 0.f);
        }
        if (DO_LN) {
            float s = 0.f, q = 0.f;
#pragma unroll
            for (int j = 0; j < 8; j++) { s += v[j]; q += v[j] * v[j]; }
#pragma unroll
            for (int o = 1; o < 16; o <<= 1) { s += __shfl_xor(s, o); q += __shfl_xor(q, o); }
            float m = s * (1.f / DIM);
            float var = q * (1.f / DIM) - m * m;
            float inv = rsqrtf(var + 1e-5f);
#pragma unroll
            for (int j = 0; j < 8; j++) v[j] = (v[j] - m) * inv * gv[j] + bbv[j];
        }
        if (WRITE_H) {
            *(float4*)(out + (size_t)r * DIM + c0) = make_float4(v[0], v[1], v[2], v[3]);
            *(float4*)(out + (size_t)r * DIM + c1) = make_float4(v[4], v[5], v[6], v[7]);
        }
        if (DO_STATES) {
            if (tx == 0) states_l[r] = (float)(3 - 2 * is_b[r] - is_l[r]);
        }
        if (DO_PROJ) {
            float pv[8];
            auto dotw = [&](const float* Wm, float& p0, float& p1) {
                float4 q0 = *(const float4*)(Wm + c0 * 2);
                float4 q1 = *(const float4*)(Wm + c0 * 2 + 4);
                float4 q2 = *(const float4*)(Wm + c1 * 2);
                float4 q3 = *(const float4*)(Wm + c1 * 2 + 4);
                p0 = v[0]*q0.x + v[1]*q0.z + v[2]*q1.x + v[3]*q1.z
                   + v[4]*q2.x + v[5]*q2.z + v[6]*q3.x + v[7]*q3.z;
                p1 = v[0]*q0.y + v[1]*q0.w + v[2]*q1.y + v[3]*q1.w
                   + v[4]*q2.y + v[5]*q2.w + v[6]*q3.y + v[7]*q3.w;
            };
            dotw(Wain, pv[0], pv[1]);
            dotw(Waon, pv[2], pv[3]);
            dotw(Wair, pv[4], pv[5]);
            dotw(Waor, pv[6], pv[7]);
#pragma unroll
            for (int o = 1; o < 16; o <<= 1)
#pragma unroll
                for (int j = 0; j < 8; j++) pv[j] += __shfl_xor(pv[j], o);
            if (tx == 0) {
                *(float4*)(proj + (size_t)r * 8)     = make_float4(pv[0], pv[1], pv[2], pv[3]);
                *(float4*)(proj + (size_t)r * 8 + 4) = make_float4(pv[4], pv[5], pv[6], pv[7]);
            }
        }
        if (DO_DEC) {
            float p[NCLS];
#pragma unroll
            for (int c = 0; c < NCLS; c++) {
                float4 wd0 = *(const float4*)&sWd[c * DIM + c0];
                float4 wd1 = *(const float4*)&sWd[c * DIM + c1];
                p[c] = v[0]*wd0.x + v[1]*wd0.y + v[2]*wd0.z + v[3]*wd0.w
                     + v[4]*wd1.x + v[5]*wd1.y + v[6]*wd1.z + v[7]*wd1.w;
            }
#pragma unroll
            for (int o = 1; o < 16; o <<= 1)
#pragma unroll
                for (int c = 0; c < NCLS; c++) p[c] += __shfl_xor(p[c], o);
            if (tx == 0) {
#pragma unroll
                for (int c = 0; c < NCLS; c++) dec_out[(size_t)r * NCLS + c] = p[c] + bdec[c];
            }
        }
    }
}

// ---------------- launcher ----------------
extern "C" void kernel_launch(void* const* d_in, const int* in_sizes, int n_in,
                              void* d_out, int out_size, void* d_ws, size_t ws_size,
                              hipStream_t stream) {
    const float* x      = (const float*)d_in[0];
    const int*   ei     = (const int*)d_in[1];
    const float* W_enc  = (const float*)d_in[2];
    const float* b_enc  = (const float*)d_in[3];
    const float* ln_g   = (const float*)d_in[4];
    const float* ln_b   = (const float*)d_in[5];
    const float* Wr     = (const float*)d_in[6];
    const float* Wn     = (const float*)d_in[7];
    const float* bl     = (const float*)d_in[8];
    const float* Wair   = (const float*)d_in[9];
    const float* Wain   = (const float*)d_in[10];
    const float* bain   = (const float*)d_in[11];
    const float* Waor   = (const float*)d_in[12];
    const float* Waon   = (const float*)d_in[13];
    const float* baon   = (const float*)d_in[14];
    const float* W_dec  = (const float*)d_in[15];
    const float* b_dec  = (const float*)d_in[16];
    const float* gin    = (const float*)d_in[17];
    const float* gout   = (const float*)d_in[18];

    int n = in_sizes[0] / DIM;
    int E = in_sizes[1] / 2;
    const int L = 3;

    char* wsp = (char*)d_ws;
    auto alloc = [&](size_t bytes) { char* p = wsp; wsp += (bytes + 255) / 256 * 256; return p; };
    float* hn   = (float*)alloc((size_t)n * DIM * 4);
    float* aggw = (float*)alloc((size_t)n * DIM * 4);
    float* proj = (float*)alloc((size_t)n * 8 * 4);
    int* deg       = (int*)alloc((size_t)n * 4);
    int* row_start = (int*)alloc((size_t)(n + 1) * 4);
    int* cursor    = (int*)alloc((size_t)n * 4);
    int* csr       = (int*)alloc((size_t)E * 4);
    int* in_bit    = (int*)alloc((size_t)n * 4);
    int* out_bit   = (int*)alloc((size_t)n * 4);
    int* bsum      = (int*)alloc((size_t)256 * 4);
    int* is_b      = (int*)alloc((size_t)n * 4);
    int* is_l      = (int*)alloc((size_t)n * 4);

    float* out_res    = (float*)d_out;                 // [n,10]
    float* out_states = out_res + (size_t)n * NCLS;    // [L,n] as float

    int ebl = (E + 255) / 256;
    int nbl = (n + 255) / 256;
    int wbl = (n + 3) / 4;        // 4 waves (nodes) per 256-thread block
    int gbl = (n + 63) / 64;      // 64-row GEMM tiles -> 782 blocks
    int nb  = (n + 1023) / 1024;  // scan blocks

    hipMemsetAsync(deg, 0, (size_t)n * 4, stream);
    k_hist<<<ebl, 256, 0, stream>>>(ei, E, deg);
    k_scan1<<<nb, 256, 0, stream>>>(deg, row_start, bsum, n);
    k_scan2<<<1, 64, 0, stream>>>(bsum, nb);
    k_scan3<<<(n + 256) / 256, 256, 0, stream>>>(row_start, cursor, bsum, n, E);
    k_fill<<<ebl, 256, 0, stream>>>(ei, E, cursor, csr);

    // encoder: hn = LN(relu(x@W_enc + b)); emits proj for layer 0
    k_gemm<0, 0, 1, 1, 0, 0, 1><<<gbl, 256, 0, stream>>>(
        x, W_enc, nullptr, nullptr, b_enc, ln_g, ln_b,
        Wain, Waon, Wair, Waor, nullptr, nullptr, nullptr, nullptr,
        hn, proj, nullptr, nullptr, n);

    for (int l = 0; l < L; l++) {
        k_action<<<nbl, 256, 0, stream>>>(proj, row_start, csr, bain, baon,
                                          gin + (size_t)l * n * 2, gout + (size_t)l * n * 2,
                                          in_bit, out_bit, is_b, n);
        k_aggw<<<wbl, 256, 0, stream>>>(hn, row_start, csr, in_bit, out_bit,
                                        is_b, is_l, aggw, n);
        if (l + 1 < L) {
            // hn = LN(hn + relu(hn@Wr + aggw@Wn + bl)); proj for next layer; states[l]
            k_gemm<1, 1, 1, 1, 1, 0, 1><<<gbl, 256, 0, stream>>>(
                hn, Wr + (size_t)l * DIM * DIM, aggw, Wn + (size_t)l * DIM * DIM,
                bl + (size_t)l * DIM, ln_g, ln_b,
                Wain, Waon, Wair, Waor, is_b, is_l, nullptr, nullptr,
                hn, proj, out_states + (size_t)l * n, nullptr, n);
        } else {
            // last layer: no hn write, no proj; fused decoder -> out_res; states[l]
            k_gemm<1, 1, 1, 0, 1, 1, 0><<<gbl, 256, 0, stream>>>(
                hn, Wr + (size_t)l * DIM * DIM, aggw, Wn + (size_t)l * DIM * DIM,
                bl + (size_t)l * DIM, ln_g, ln_b,
                Wain, Waon, Wair, Waor, is_b, is_l, W_dec, b_dec,
                hn, nullptr, out_states + (size_t)l * n, out_res, n);
        }
    }
}

// Round 14
// 480.971 us; speedup vs baseline: 4.0117x; 4.0117x over previous
//
#include <hip/hip_runtime.h>

#define DIM 128
#define NCLS 10

// async global->LDS DMA (16B per lane; LDS dest = wave-uniform base + lane*16)
__device__ __forceinline__ void gload_lds16(const float4* g, float4* l) {
    __builtin_amdgcn_global_load_lds((const __attribute__((address_space(1))) char*)g,
                                     (__attribute__((address_space(3))) char*)l,
                                     16, 0, 0);
}

// ---------------- CSR build ----------------
__global__ void k_hist(const int* __restrict__ ei, int E, int* __restrict__ deg) {
    int e = blockIdx.x * 256 + threadIdx.x;
    if (e < E) atomicAdd(&deg[ei[E + e]], 1);   // v = ei[1][e]
}

__global__ void k_scan1(const int* __restrict__ deg, int* __restrict__ row_start,
                        int* __restrict__ bsum, int n) {
    int tid = threadIdx.x;
    int base = blockIdx.x * 1024 + tid * 4;
    int v0 = 0, v1 = 0, v2 = 0, v3 = 0;
    if (base + 3 < n) {
        int4 t = *(const int4*)(deg + base);
        v0 = t.x; v1 = t.y; v2 = t.z; v3 = t.w;
    } else {
        if (base + 0 < n) v0 = deg[base + 0];
        if (base + 1 < n) v1 = deg[base + 1];
        if (base + 2 < n) v2 = deg[base + 2];
        if (base + 3 < n) v3 = deg[base + 3];
    }
    int s = v0 + v1 + v2 + v3;
    int lane = tid & 63, w = tid >> 6;
    int inc = s;
#pragma unroll
    for (int o = 1; o < 64; o <<= 1) {
        int t = __shfl_up(inc, o);
        if (lane >= o) inc += t;
    }
    __shared__ int wsum[4];
    if (lane == 63) wsum[w] = inc;
    __syncthreads();
    int woff = 0;
    for (int i = 0; i < w; i++) woff += wsum[i];
    int run = woff + inc - s;
    if (base + 0 < n) row_start[base + 0] = run; run += v0;
    if (base + 1 < n) row_start[base + 1] = run; run += v1;
    if (base + 2 < n) row_start[base + 2] = run; run += v2;
    if (base + 3 < n) row_start[base + 3] = run;
    if (tid == 0) bsum[blockIdx.x] = wsum[0] + wsum[1] + wsum[2] + wsum[3];
}

__global__ void k_scan2(int* __restrict__ bsum, int nb) {
    int tid = threadIdx.x;
    if (nb <= 64) {
        int v = (tid < nb) ? bsum[tid] : 0;
        int inc = v;
#pragma unroll
        for (int o = 1; o < 64; o <<= 1) {
            int t = __shfl_up(inc, o);
            if (tid >= o) inc += t;
        }
        if (tid < nb) bsum[tid] = inc - v;
    } else if (tid == 0) {
        int acc = 0;
        for (int i = 0; i < nb; i++) { int t = bsum[i]; bsum[i] = acc; acc += t; }
    }
}

__global__ void k_scan3(int* __restrict__ row_start, int* __restrict__ cursor,
                        const int* __restrict__ bsum, int n, int E) {
    int i = blockIdx.x * 256 + threadIdx.x;
    if (i < n) {
        int r = row_start[i] + bsum[i >> 10];
        row_start[i] = r;
        cursor[i] = r;
    }
    if (i == n) row_start[n] = E;
}

__global__ void k_fill(const int* __restrict__ ei, int E, int* __restrict__ cursor,
                       int* __restrict__ csr) {
    int e = blockIdx.x * 256 + threadIdx.x;
    if (e < E) {
        int u = ei[e], v = ei[E + e];
        int pos = atomicAdd(&cursor[v], 1);
        csr[pos] = u;
    }
}

// ---------------- action gates: thread per node, 16B/neighbor gather ----------------
// Also zeroes is_b (set by k_aggw which runs next on the stream).
__global__ void k_action(const float* __restrict__ proj, const int* __restrict__ row_start,
                         const int* __restrict__ csr,
                         const float* __restrict__ bain, const float* __restrict__ baon,
                         const float* __restrict__ gin_l, const float* __restrict__ gout_l,
                         int* __restrict__ in_bit, int* __restrict__ out_bit,
                         int* __restrict__ is_b, int n) {
    int v = blockIdx.x * 256 + threadIdx.x;
    if (v >= n) return;
    is_b[v] = 0;
    int b0 = row_start[v], b1 = row_start[v + 1];
    double a0 = 0.0, a1 = 0.0, a2 = 0.0, a3 = 0.0;
    for (int e = b0; e < b1; e++) {
        int u = csr[e];
        float4 p = *(const float4*)(proj + (size_t)u * 8);
        a0 += p.x; a1 += p.y; a2 += p.z; a3 += p.w;
    }
    float4 r = *(const float4*)(proj + (size_t)v * 8 + 4);
    float2 gi = *(const float2*)(gin_l + (size_t)v * 2);
    float2 go = *(const float2*)(gout_l + (size_t)v * 2);
    float li0 = (float)a0 + r.x + bain[0] + gi.x;
    float li1 = (float)a1 + r.y + bain[1] + gi.y;
    float lo0 = (float)a2 + r.z + baon[0] + go.x;
    float lo1 = (float)a3 + r.w + baon[1] + go.y;
    in_bit[v]  = (li0 >= li1) ? 1 : 0;   // argmax==0 on tie
    out_bit[v] = (lo0 >= lo1) ? 1 : 0;
}

// ---------------- gated aggregation + is_b/is_l bookkeeping ----------------
// f64 accumulate: CSR fill order is atomic-nondeterministic; f64 makes the
// rounded f32 sums replay-stable (gate margins can be ~1e-5).
__global__ void k_aggw(const float* __restrict__ hn, const int* __restrict__ row_start,
                       const int* __restrict__ csr, const int* __restrict__ in_bit,
                       const int* __restrict__ out_bit,
                       int* __restrict__ is_b, int* __restrict__ is_l,
                       float* __restrict__ aggw, int n) {
    int wid = (blockIdx.x * 256 + threadIdx.x) >> 6;
    int lane = threadIdx.x & 63;
    if (wid >= n) return;
    int d0 = lane * 2;
    double ax = 0.0, ay = 0.0;
    int anyg = 0;
    if (in_bit[wid]) {
        int base = row_start[wid], end = row_start[wid + 1];
        for (int off = base; off < end; off += 64) {
            int m = min(64, end - off);
            int myu = 0, myb = 0;
            if (lane < m) { myu = csr[off + lane]; myb = out_bit[myu]; }
            unsigned long long mask = __ballot(myb != 0);
            anyg |= (mask != 0ull);
            while (mask) {
                int i = __ffsll((unsigned long long)mask) - 1;
                mask &= mask - 1;
                int u = __shfl(myu, i);
                if (lane == 0) is_b[u] = 1;   // benign race: same value
                float2 t = *(const float2*)(hn + (size_t)u * DIM + d0);
                ax += t.x; ay += t.y;
            }
        }
    }
    if (lane == 0) is_l[wid] = anyg;
    ((float2*)(aggw + (size_t)wid * DIM))[lane] = make_float2((float)ax, (float)ay);
}

// ---------------- GEMM: 64x128 tile, 256 threads, TM=4 x TN=8 ----------------
// out = [LN]( [A +] relu(A@W1 [+ B@W2] + bias) )
// r8 base (best verified: 85us/layer, VGPR 64, zero spill) with ONE change:
// W staging via __builtin_amdgcn_global_load_lds (async DMA, no VGPR round-trip,
// no ds_writes). W layout is linear float4s -> satisfies the wave-uniform-base +
// lane*16 LDS-dest rule. A keeps the register path (pad-36 layout is not linear).
// Register-prefetch double-buffering is permanently abandoned: r3 and r13 both
// spilled catastrophically (WRITE_SIZE 79MB/1.2GB) — the 24-reg prefetch cannot
// stay live across the 1024-FMA compute loop under any waves_per_eu setting.
// Row r's 128 cols live in the 16 lanes sharing ty -> shfl_xor(1,2,4,8) row
// reduce (LN, PROJ, DEC). In-place safe (out==A): block only touches own rows.
template <int HAS_B, int SKIP, int DO_LN, int DO_PROJ, int DO_STATES, int DO_DEC, int WRITE_H>
__launch_bounds__(256)
__attribute__((amdgpu_waves_per_eu(4, 4)))
__global__ void k_gemm(const float* __restrict__ A, const float* __restrict__ W1,
                       const float* __restrict__ B, const float* __restrict__ W2,
                       const float* __restrict__ bias,
                       const float* __restrict__ ln_g, const float* __restrict__ ln_b,
                       const float* __restrict__ Wain, const float* __restrict__ Waon,
                       const float* __restrict__ Wair, const float* __restrict__ Waor,
                       const int* __restrict__ is_b, const int* __restrict__ is_l,
                       const float* __restrict__ Wdec, const float* __restrict__ bdec,
                       float* __restrict__ out, float* __restrict__ proj,
                       float* __restrict__ states_l, float* __restrict__ dec_out, int n) {
    __shared__ float sW[32][128];
    __shared__ float sA[64][36];
    int tid = threadIdx.x;
    int rowBase = blockIdx.x * 64;
    int ty = tid >> 4, tx = tid & 15;
    int c0 = tx * 4, c1 = 64 + tx * 4;
    float acc[4][8];
#pragma unroll
    for (int i = 0; i < 4; i++)
#pragma unroll
        for (int j = 0; j < 8; j++) acc[i][j] = 0.f;

    for (int p = 0; p < 1 + HAS_B; p++) {
        const float* Ap = p ? B : A;
        const float* Wp = p ? W2 : W1;
        for (int kc = 0; kc < DIM; kc += 32) {
            __syncthreads();
            {   // W chunk 32x128: async DMA (4 x 16B/thread, linear)
                const float4* src = (const float4*)(Wp + kc * DIM);
                float4* dst = (float4*)(&sW[0][0]);
#pragma unroll
                for (int i = 0; i < 4; i++) {
                    int j = i * 256 + tid;
                    gload_lds16(src + j, dst + j);
                }
            }
            {   // A tile 64x32: register path (padded LDS layout)
#pragma unroll
                for (int i = 0; i < 2; i++) {
                    int j = i * 256 + tid;
                    int r = j >> 3, c4 = (j & 7) * 4;
                    float4 va = (rowBase + r < n)
                        ? *(const float4*)(Ap + (size_t)(rowBase + r) * DIM + kc + c4)
                        : make_float4(0.f, 0.f, 0.f, 0.f);
                    *(float4*)&sA[r][c4] = va;
                }
            }
            __syncthreads();
#pragma unroll
            for (int kk = 0; kk < 32; kk += 4) {
                // stage A fragments: 4 float4 (16 regs), 16-lane broadcast reads
                float4 a[4];
#pragma unroll
                for (int i = 0; i < 4; i++) a[i] = *(const float4*)&sA[i * 16 + ty][kk];
                // W loaded per-q (8 regs live), reused by all 4 rows
#pragma unroll
                for (int q = 0; q < 4; q++) {
                    float4 w0 = *(const float4*)&sW[kk + q][c0];
                    float4 w1 = *(const float4*)&sW[kk + q][c1];
#pragma unroll
                    for (int i = 0; i < 4; i++) {
                        float av = (&a[i].x)[q];
                        acc[i][0] += av * w0.x;
                        acc[i][1] += av * w0.y;
                        acc[i][2] += av * w0.z;
                        acc[i][3] += av * w0.w;
                        acc[i][4] += av * w1.x;
                        acc[i][5] += av * w1.y;
                        acc[i][6] += av * w1.z;
                        acc[i][7] += av * w1.w;
                    }
                }
            }
        }
    }

    // ---- decoder weight staging (reuses sW space; main loop done with it) ----
    float* sWd = (float*)&sW[0][0];   // [NCLS][DIM] transposed
    if (DO_DEC) {
        __syncthreads();
        for (int i = tid; i < NCLS * DIM; i += 256) {
            int d = i / NCLS, c = i % NCLS;
            sWd[c * DIM + d] = Wdec[i];
        }
        __syncthreads();
    }

    float4 bias0 = *(const float4*)&bias[c0];
    float4 bias1 = *(const float4*)&bias[c1];
    float bv[8] = {bias0.x, bias0.y, bias0.z, bias0.w, bias1.x, bias1.y, bias1.z, bias1.w};
    float gv[8], bbv[8];
    if (DO_LN) {
        float4 g0 = *(const float4*)&ln_g[c0];
        float4 g1 = *(const float4*)&ln_g[c1];
        float4 lb0 = *(const float4*)&ln_b[c0];
        float4 lb1 = *(const float4*)&ln_b[c1];
        gv[0]=g0.x; gv[1]=g0.y; gv[2]=g0.z; gv[3]=g0.w; gv[4]=g1.x; gv[5]=g1.y; gv[6]=g1.z; gv[7]=g1.w;
        bbv[0]=lb0.x; bbv[1]=lb0.y; bbv[2]=lb0.z; bbv[3]=lb0.w; bbv[4]=lb1.x; bbv[5]=lb1.y; bbv[6]=lb1.z; bbv[7]=lb1.w;
    }

#pragma unroll
    for (int i = 0; i < 4; i++) {
        int r = rowBase + i * 16 + ty;
        if (r >= n) continue;   // uniform across the 16 lanes sharing ty
        float v[8];
        if (SKIP) {
            float4 s0 = *(const float4*)(A + (size_t)r * DIM + c0);
            float4 s1 = *(const float4*)(A + (size_t)r * DIM + c1);
            float sv[8] = {s0.x, s0.y, s0.z, s0.w, s1.x, s1.y, s1.z, s1.w};
#pragma unroll
            for (int j = 0; j < 8; j++) v[j] = fmaxf(acc[i][j] + bv[j], 0.f) + sv[j];
        } else {
#pragma unroll
            for (int j = 0; j < 8; j++) v[j] = fmaxf(acc[i][j] + bv[j], 0.f);
        }
        if (DO_LN) {
            float s = 0.f, q = 0.f;
#pragma unroll
            for (int j = 0; j < 8; j++) { s += v[j]; q += v[j] * v[j]; }
#pragma unroll
            for (int o = 1; o < 16; o <<= 1) { s += __shfl_xor(s, o); q += __shfl_xor(q, o); }
            float m = s * (1.f / DIM);
            float var = q * (1.f / DIM) - m * m;
            float inv = rsqrtf(var + 1e-5f);
#pragma unroll
            for (int j = 0; j < 8; j++) v[j] = (v[j] - m) * inv * gv[j] + bbv[j];
        }
        if (WRITE_H) {
            *(float4*)(out + (size_t)r * DIM + c0) = make_float4(v[0], v[1], v[2], v[3]);
            *(float4*)(out + (size_t)r * DIM + c1) = make_float4(v[4], v[5], v[6], v[7]);
        }
        if (DO_STATES) {
            if (tx == 0) states_l[r] = (float)(3 - 2 * is_b[r] - is_l[r]);
        }
        if (DO_PROJ) {
            float pv[8];
            auto dotw = [&](const float* Wm, float& p0, float& p1) {
                float4 q0 = *(const float4*)(Wm + c0 * 2);
                float4 q1 = *(const float4*)(Wm + c0 * 2 + 4);
                float4 q2 = *(const float4*)(Wm + c1 * 2);
                float4 q3 = *(const float4*)(Wm + c1 * 2 + 4);
                p0 = v[0]*q0.x + v[1]*q0.z + v[2]*q1.x + v[3]*q1.z
                   + v[4]*q2.x + v[5]*q2.z + v[6]*q3.x + v[7]*q3.z;
                p1 = v[0]*q0.y + v[1]*q0.w + v[2]*q1.y + v[3]*q1.w
                   + v[4]*q2.y + v[5]*q2.w + v[6]*q3.y + v[7]*q3.w;
            };
            dotw(Wain, pv[0], pv[1]);
            dotw(Waon, pv[2], pv[3]);
            dotw(Wair, pv[4], pv[5]);
            dotw(Waor, pv[6], pv[7]);
#pragma unroll
            for (int o = 1; o < 16; o <<= 1)
#pragma unroll
                for (int j = 0; j < 8; j++) pv[j] += __shfl_xor(pv[j], o);
            if (tx == 0) {
                *(float4*)(proj + (size_t)r * 8)     = make_float4(pv[0], pv[1], pv[2], pv[3]);
                *(float4*)(proj + (size_t)r * 8 + 4) = make_float4(pv[4], pv[5], pv[6], pv[7]);
            }
        }
        if (DO_DEC) {
            float p[NCLS];
#pragma unroll
            for (int c = 0; c < NCLS; c++) {
                float4 wd0 = *(const float4*)&sWd[c * DIM + c0];
                float4 wd1 = *(const float4*)&sWd[c * DIM + c1];
                p[c] = v[0]*wd0.x + v[1]*wd0.y + v[2]*wd0.z + v[3]*wd0.w
                     + v[4]*wd1.x + v[5]*wd1.y + v[6]*wd1.z + v[7]*wd1.w;
            }
#pragma unroll
            for (int o = 1; o < 16; o <<= 1)
#pragma unroll
                for (int c = 0; c < NCLS; c++) p[c] += __shfl_xor(p[c], o);
            if (tx == 0) {
#pragma unroll
                for (int c = 0; c < NCLS; c++) dec_out[(size_t)r * NCLS + c] = p[c] + bdec[c];
            }
        }
    }
}

// ---------------- launcher ----------------
extern "C" void kernel_launch(void* const* d_in, const int* in_sizes, int n_in,
                              void* d_out, int out_size, void* d_ws, size_t ws_size,
                              hipStream_t stream) {
    const float* x      = (const float*)d_in[0];
    const int*   ei     = (const int*)d_in[1];
    const float* W_enc  = (const float*)d_in[2];
    const float* b_enc  = (const float*)d_in[3];
    const float* ln_g   = (const float*)d_in[4];
    const float* ln_b   = (const float*)d_in[5];
    const float* Wr     = (const float*)d_in[6];
    const float* Wn     = (const float*)d_in[7];
    const float* bl     = (const float*)d_in[8];
    const float* Wair   = (const float*)d_in[9];
    const float* Wain   = (const float*)d_in[10];
    const float* bain   = (const float*)d_in[11];
    const float* Waor   = (const float*)d_in[12];
    const float* Waon   = (const float*)d_in[13];
    const float* baon   = (const float*)d_in[14];
    const float* W_dec  = (const float*)d_in[15];
    const float* b_dec  = (const float*)d_in[16];
    const float* gin    = (const float*)d_in[17];
    const float* gout   = (const float*)d_in[18];

    int n = in_sizes[0] / DIM;
    int E = in_sizes[1] / 2;
    const int L = 3;

    char* wsp = (char*)d_ws;
    auto alloc = [&](size_t bytes) { char* p = wsp; wsp += (bytes + 255) / 256 * 256; return p; };
    float* hn   = (float*)alloc((size_t)n * DIM * 4);
    float* aggw = (float*)alloc((size_t)n * DIM * 4);
    float* proj = (float*)alloc((size_t)n * 8 * 4);
    int* deg       = (int*)alloc((size_t)n * 4);
    int* row_start = (int*)alloc((size_t)(n + 1) * 4);
    int* cursor    = (int*)alloc((size_t)n * 4);
    int* csr       = (int*)alloc((size_t)E * 4);
    int* in_bit    = (int*)alloc((size_t)n * 4);
    int* out_bit   = (int*)alloc((size_t)n * 4);
    int* bsum      = (int*)alloc((size_t)256 * 4);
    int* is_b      = (int*)alloc((size_t)n * 4);
    int* is_l      = (int*)alloc((size_t)n * 4);

    float* out_res    = (float*)d_out;                 // [n,10]
    float* out_states = out_res + (size_t)n * NCLS;    // [L,n] as float

    int ebl = (E + 255) / 256;
    int nbl = (n + 255) / 256;
    int wbl = (n + 3) / 4;        // 4 waves (nodes) per 256-thread block
    int gbl = (n + 63) / 64;      // 64-row GEMM tiles -> 782 blocks
    int nb  = (n + 1023) / 1024;  // scan blocks

    hipMemsetAsync(deg, 0, (size_t)n * 4, stream);
    k_hist<<<ebl, 256, 0, stream>>>(ei, E, deg);
    k_scan1<<<nb, 256, 0, stream>>>(deg, row_start, bsum, n);
    k_scan2<<<1, 64, 0, stream>>>(bsum, nb);
    k_scan3<<<(n + 256) / 256, 256, 0, stream>>>(row_start, cursor, bsum, n, E);
    k_fill<<<ebl, 256, 0, stream>>>(ei, E, cursor, csr);

    // encoder: hn = LN(relu(x@W_enc + b)); emits proj for layer 0
    k_gemm<0, 0, 1, 1, 0, 0, 1><<<gbl, 256, 0, stream>>>(
        x, W_enc, nullptr, nullptr, b_enc, ln_g, ln_b,
        Wain, Waon, Wair, Waor, nullptr, nullptr, nullptr, nullptr,
        hn, proj, nullptr, nullptr, n);

    for (int l = 0; l < L; l++) {
        k_action<<<nbl, 256, 0, stream>>>(proj, row_start, csr, bain, baon,
                                          gin + (size_t)l * n * 2, gout + (size_t)l * n * 2,
                                          in_bit, out_bit, is_b, n);
        k_aggw<<<wbl, 256, 0, stream>>>(hn, row_start, csr, in_bit, out_bit,
                                        is_b, is_l, aggw, n);
        if (l + 1 < L) {
            // hn = LN(hn + relu(hn@Wr + aggw@Wn + bl)); proj for next layer; states[l]
            k_gemm<1, 1, 1, 1, 1, 0, 1><<<gbl, 256, 0, stream>>>(
                hn, Wr + (size_t)l * DIM * DIM, aggw, Wn + (size_t)l * DIM * DIM,
                bl + (size_t)l * DIM, ln_g, ln_b,
                Wain, Waon, Wair, Waor, is_b, is_l, nullptr, nullptr,
                hn, proj, out_states + (size_t)l * n, nullptr, n);
        } else {
            // last layer: no hn write, no proj; fused decoder -> out_res; states[l]
            k_gemm<1, 1, 1, 0, 1, 1, 0><<<gbl, 256, 0, stream>>>(
                hn, Wr + (size_t)l * DIM * DIM, aggw, Wn + (size_t)l * DIM * DIM,
                bl + (size_t)l * DIM, ln_g, ln_b,
                Wain, Waon, Wair, Waor, is_b, is_l, W_dec, b_dec,
                hn, nullptr, out_states + (size_t)l * n, out_res, n);
        }
    }
}